// Round 6
// baseline (272.520 us; speedup 1.0000x reference)
//
#include <hip/hip_runtime.h>
#include <hip/hip_bf16.h>

#define DIMC 1536
#define NHC 16
#define HDC 96
#define BC 2
#define SC 2048
#define BSC (BC*SC)   // 4096 rows total

typedef __bf16 bf16x8 __attribute__((ext_vector_type(8)));
typedef __bf16 bf16x4 __attribute__((ext_vector_type(4)));
typedef float f32x4 __attribute__((ext_vector_type(4)));

// async global->LDS, 16B per lane: lane i -> lds_base + i*16 (lds base wave-uniform)
#define GLL(g, l)                                                              \
  __builtin_amdgcn_global_load_lds(                                            \
      (const __attribute__((address_space(1))) unsigned int*)(const void*)(g), \
      (__attribute__((address_space(3))) unsigned int*)(void*)(l), 16, 0, 0)

// (1/sqrt(96)) * log2(e): Q is pre-scaled by this so attention uses exp2 directly
#define QSCALE 0.14724448646421423f

// ---------------------------------------------------------------------------
// Flat fp32->bf16 conversion for h + 4 weights (grid-stride over vec8 jobs)
// + RoPE table: rt[(row*3+axis)*16+f] = (cos,sin) of xyz[..]*10000^(-f/16)
// ---------------------------------------------------------------------------
#define NV0 786432            // h: 4096*1536/8
#define NVW 294912            // each weight: 1536*1536/8
#define NVALL (NV0 + 4*NVW)   // 1966080

__global__ __launch_bounds__(256) void cvt_bf16_k(
    const float* __restrict__ s0, const float* __restrict__ s1,
    const float* __restrict__ s2, const float* __restrict__ s3,
    const float* __restrict__ s4,
    __bf16* __restrict__ d0, __bf16* __restrict__ d1, __bf16* __restrict__ d2,
    __bf16* __restrict__ d3, __bf16* __restrict__ d4,
    const int* __restrict__ xyz, float2* __restrict__ rt) {
  int tid = blockIdx.x * 256 + threadIdx.x;
  int stride = gridDim.x * 256;
  for (int j = tid; j < NVALL; j += stride) {
    const float* src;
    __bf16* dst;
    int base;
    if (j < NV0) {
      src = s0; dst = d0; base = j;
    } else {
      int u = j - NV0;
      int r = u / NVW;
      base = u - r * NVW;
      src = (r == 0) ? s1 : (r == 1) ? s2 : (r == 2) ? s3 : s4;
      dst = (r == 0) ? d1 : (r == 1) ? d2 : (r == 2) ? d3 : d4;
    }
    int idx = base * 8;
    float4 a = *(const float4*)(src + idx);
    float4 b = *(const float4*)(src + idx + 4);
    __bf16 o[8];
    o[0] = (__bf16)a.x; o[1] = (__bf16)a.y; o[2] = (__bf16)a.z; o[3] = (__bf16)a.w;
    o[4] = (__bf16)b.x; o[5] = (__bf16)b.y; o[6] = (__bf16)b.z; o[7] = (__bf16)b.w;
    *(uint4*)(dst + idx) = *(const uint4*)o;
  }
  for (int j = tid; j < BSC * 48; j += stride) {
    int f = j & 15;
    int ra = j >> 4;  // row*3 + axis
    float invf = exp2f(-0.8304820237f * (float)f);
    float ang = (float)xyz[ra] * invf;
    float sn, cs;
    __sincosf(ang, &sn, &cs);
    rt[j] = make_float2(cs, sn);
  }
}

// ---------------------------------------------------------------------------
// GEMM core: C[4096,1536] = A * Bm^T, 128x128 tile, BK=64, GLL staging,
// XOR-swizzled LDS (row stride 64 elems = 128B; chunk' = chunk ^ (row&7)).
// ---------------------------------------------------------------------------
__device__ __forceinline__ void gemm_core(const __bf16* __restrict__ A,
                                          const __bf16* __restrict__ Bm,
                                          int bm, int bn, f32x4 acc[4][4],
                                          __bf16* As, __bf16* Bs) {
  const int t = threadIdx.x;
  const int wave = t >> 6, lane = t & 63;
  const int l15 = lane & 15, l4 = lane >> 4;
  const int wm = (wave >> 1) * 64, wn = (wave & 1) * 64;

  const int srow8 = lane >> 3;                 // 0..7
  const int scol = ((lane & 7) ^ srow8) * 8;   // swizzled global col chunk
  const __bf16* gA = A + (size_t)(bm * 128 + wave * 32 + srow8) * DIMC + scol;
  const __bf16* gB = Bm + (size_t)(bn * 128 + wave * 32 + srow8) * DIMC + scol;
  __bf16* lA = As + wave * 2048;
  __bf16* lB = Bs + wave * 2048;

  for (int k0 = 0; k0 < DIMC; k0 += 64) {
    __syncthreads();
#pragma unroll
    for (int c = 0; c < 4; c++) {
      GLL(gA + c * 8 * DIMC, lA + c * 512);
      GLL(gB + c * 8 * DIMC, lB + c * 512);
    }
    gA += 64; gB += 64;
    __syncthreads();
#pragma unroll
    for (int k2 = 0; k2 < 2; k2++) {
      bf16x8 af[4], bfr[4];
#pragma unroll
      for (int i = 0; i < 4; i++) {
        int row = wm + i * 16 + l15;
        af[i] = *(const bf16x8*)&As[row * 64 + (((k2 * 4 + l4) ^ (l15 & 7)) * 8)];
      }
#pragma unroll
      for (int j = 0; j < 4; j++) {
        int row = wn + j * 16 + l15;
        bfr[j] = *(const bf16x8*)&Bs[row * 64 + (((k2 * 4 + l4) ^ (l15 & 7)) * 8)];
      }
#pragma unroll
      for (int i = 0; i < 4; i++)
#pragma unroll
        for (int j = 0; j < 4; j++)
          acc[i][j] = __builtin_amdgcn_mfma_f32_16x16x32_bf16(af[i], bfr[j], acc[i][j], 0, 0, 0);
    }
  }
}

// QKV GEMM: z=0 -> q (rope, pre-scaled), z=1 -> k (rope), z=2 -> v transposed to vT[bh][d][s]
__global__ __launch_bounds__(256, 2) void gemm_qkv_k(
    const __bf16* __restrict__ A, const __bf16* __restrict__ W0,
    const __bf16* __restrict__ W1, const __bf16* __restrict__ W2,
    const float2* __restrict__ rt,
    __bf16* __restrict__ qo, __bf16* __restrict__ ko, __bf16* __restrict__ vT) {
  __shared__ __bf16 As[128 * 64];
  __shared__ __bf16 Bs[128 * 64];
  const int z = blockIdx.z;
  const __bf16* W = (z == 0) ? W0 : (z == 1) ? W1 : W2;
  f32x4 acc[4][4] = {};
  gemm_core(A, W, blockIdx.x, blockIdx.y, acc, As, Bs);

  const int t = threadIdx.x;
  const int wave = t >> 6, lane = t & 63;
  const int l15 = lane & 15, l4 = lane >> 4;
  const int wm = (wave >> 1) * 64, wn = (wave & 1) * 64;

  if (z < 2) {
    __bf16* C = (z == 0) ? qo : ko;
    const float qs = (z == 0) ? QSCALE : 1.0f;
#pragma unroll
    for (int jp = 0; jp < 2; jp++) {
      int colbase = blockIdx.y * 128 + wn + jp * 32;
      int axis = (colbase % 96) >> 5;  // wave-uniform
#pragma unroll
      for (int i = 0; i < 4; i++) {
#pragma unroll
        for (int r = 0; r < 4; r++) {
          int row = blockIdx.x * 128 + wm + i * 16 + l4 * 4 + r;
          float2 t2 = rt[(row * 3 + axis) * 16 + l15];
          float e = acc[i][2 * jp][r], od = acc[i][2 * jp + 1][r];
          C[(size_t)row * DIMC + colbase + l15] = (__bf16)((e * t2.x - od * t2.y) * qs);
          C[(size_t)row * DIMC + colbase + l15 + 16] = (__bf16)((od * t2.x + e * t2.y) * qs);
        }
      }
    }
  } else {
#pragma unroll
    for (int i = 0; i < 4; i++)
#pragma unroll
      for (int j = 0; j < 4; j++) {
        int row0 = blockIdx.x * 128 + wm + i * 16 + l4 * 4;
        int col = blockIdx.y * 128 + wn + j * 16 + l15;
        int head = col / 96, d = col % 96;
        int b = row0 >> 11, s = row0 & 2047;
        bf16x4 pk;
#pragma unroll
        for (int r = 0; r < 4; r++) pk[r] = (__bf16)acc[i][j][r];
        *(bf16x4*)(vT + ((size_t)(b * 16 + head) * 96 + d) * 2048 + s) = pk;
      }
  }
}

__global__ __launch_bounds__(256, 2) void gemm_out_k(const __bf16* __restrict__ A,
                                                     const __bf16* __restrict__ W,
                                                     float* __restrict__ C) {
  __shared__ __bf16 As[128 * 64];
  __shared__ __bf16 Bs[128 * 64];
  f32x4 acc[4][4] = {};
  gemm_core(A, W, blockIdx.x, blockIdx.y, acc, As, Bs);
  const int t = threadIdx.x;
  const int wave = t >> 6, lane = t & 63;
  const int l15 = lane & 15, l4 = lane >> 4;
  const int wm = (wave >> 1) * 64, wn = (wave & 1) * 64;
#pragma unroll
  for (int i = 0; i < 4; i++)
#pragma unroll
    for (int j = 0; j < 4; j++) {
      int row = blockIdx.x * 128 + wm + i * 16 + l4 * 4;
      int col = blockIdx.y * 128 + wn + j * 16 + l15;
#pragma unroll
      for (int r = 0; r < 4; r++)
        C[(size_t)(row + r) * DIMC + col] = acc[i][j][r];
    }
}

// ---------------------------------------------------------------------------
// Flash attention, linear softmax (exp2, Q pre-scaled), SOFTWARE-PIPELINED:
// at iter kt, S(kt+1) (QK^T MFMAs from resident K) runs concurrently with
// PV(kt) (P from wave-private LDS written last iter, V resident) — two
// independent streams per wave, hiding the ds_read/exp chains at the fixed
// 2 waves/SIMD occupancy (VGPR-capped by the 64qx96d fp32 O accumulator).
// 512 thr = 2 key-groups x 4 waves; group g covers keys [g*1024,(g+1)*1024)
// in 32-key tiles; wave owns 64 q rows. K double-buffered, V TRIPLE-buffered
// (GLL(kt+2) must not clobber V(kt) in use). One barrier per iter.
// ---------------------------------------------------------------------------
#define PSTR 40  // P row stride (elems)

__global__ __launch_bounds__(512, 2) void attn_k(const __bf16* __restrict__ q,
                                                 const __bf16* __restrict__ k,
                                                 const __bf16* __restrict__ vT,
                                                 __bf16* __restrict__ o) {
  const int qt = blockIdx.x;    // 0..7 (256 q rows each)
  const int bh = blockIdx.y;
  const int b = bh >> 4, h = bh & 15;
  const int t = threadIdx.x;
  const int wave = t >> 6, lane = t & 63;
  const int l15 = lane & 15, l4 = lane >> 4;
  const int grp = wave >> 2, wgrp = wave & 3;

  // LDS: Kb[2][2grp][3072] | Vb[3][2grp][3072] | Ps[8][2560] | Ls[2][256]
  // merge phase reuses bytes [0, 98304) as FB = float[4][64*96]
  __shared__ __attribute__((aligned(16))) char smem[104448];
  __bf16* Ks = (__bf16*)smem;                    // 24576 B
  __bf16* Vs = (__bf16*)(smem + 24576);          // 36864 B
  __bf16* Ps = (__bf16*)(smem + 61440);          // 40960 B
  float* Ls = (float*)(smem + 102400);           // 2048 B
  float* FB = (float*)smem;

  // Q fragments (persist): q rows = qt*256 + wgrp*64 + mt*16 + l15
  bf16x8 qf[4][3];
  {
    const __bf16* gq =
        q + (size_t)(b * SC + qt * 256 + wgrp * 64 + l15) * DIMC + h * HDC + l4 * 8;
#pragma unroll
    for (int mt = 0; mt < 4; mt++)
#pragma unroll
      for (int ks = 0; ks < 3; ks++)
        qf[mt][ks] = *(const bf16x8*)(gq + (size_t)mt * 16 * DIMC + ks * 32);
  }

  // staging: waves 0-1 of each group stage K (32x96), waves 2-3 stage V (96x32)
  const bool isK = (wgrp < 2);
  const int cw = isK ? wgrp : (wgrp - 2);
  const __bf16* gbase = isK ? k : vT;
  const int inc = isK ? 32 * DIMC : 32;
  int goffs[3];
  int ldoffs[3];
#pragma unroll
  for (int r = 0; r < 3; r++) {
    int off = (cw * 3 + r) * 512 + lane * 8;
    ldoffs[r] = (cw * 3 + r) * 512;
    if (isK) {
      int key = off / 96, d = off % 96;
      goffs[r] = (b * SC + grp * 1024 + key) * DIMC + h * HDC + d;
    } else {
      int d = off >> 5, key = off & 31;
      goffs[r] = (bh * HDC + d) * SC + grp * 1024 + key;
    }
  }
  __bf16* stK0 = Ks + grp * 3072;  // buffer slot 0 base for this group (K)
  __bf16* stV0 = Vs + grp * 3072;  // (V); slot i adds i*6144

  f32x4 oacc[4][6] = {};
  float lacc[4] = {0.f, 0.f, 0.f, 0.f};
  __bf16* Pw = Ps + wave * 2560;

  // ---- prologue: stage tile 0 ----
#pragma unroll
  for (int r = 0; r < 3; r++) GLL(gbase + goffs[r], (isK ? stK0 : stV0) + ldoffs[r]);
#pragma unroll
  for (int r = 0; r < 3; r++) goffs[r] += inc;
  __syncthreads();  // tile 0 resident

  // S(0) + P(0)
  {
    const __bf16* Kc = Ks + grp * 3072;
#pragma unroll
    for (int kk = 0; kk < 2; kk++) {
      bf16x8 kf[3];
#pragma unroll
      for (int ks = 0; ks < 3; ks++)
        kf[ks] = *(const bf16x8*)&Kc[(kk * 16 + l15) * 96 + ks * 32 + l4 * 8];
      f32x4 sacc[4] = {};
#pragma unroll
      for (int ks = 0; ks < 3; ks++)
#pragma unroll
        for (int mt = 0; mt < 4; mt++)
          sacc[mt] = __builtin_amdgcn_mfma_f32_16x16x32_bf16(kf[ks], qf[mt][ks], sacc[mt], 0, 0, 0);
#pragma unroll
      for (int mt = 0; mt < 4; mt++) {
        float p0 = __builtin_amdgcn_exp2f(sacc[mt][0]);
        float p1 = __builtin_amdgcn_exp2f(sacc[mt][1]);
        float p2 = __builtin_amdgcn_exp2f(sacc[mt][2]);
        float p3 = __builtin_amdgcn_exp2f(sacc[mt][3]);
        lacc[mt] += (p0 + p1) + (p2 + p3);
        bf16x4 pb;
        pb[0] = (__bf16)p0; pb[1] = (__bf16)p1; pb[2] = (__bf16)p2; pb[3] = (__bf16)p3;
        *(bf16x4*)&Pw[(mt * 16 + l15) * PSTR + kk * 16 + l4 * 4] = pb;
      }
    }
  }
  // stage tile 1 (K slot 1, V slot 1)
#pragma unroll
  for (int r = 0; r < 3; r++)
    GLL(gbase + goffs[r], (isK ? (stK0 + 6144) : (stV0 + 6144)) + ldoffs[r]);
#pragma unroll
  for (int r = 0; r < 3; r++) goffs[r] += inc;
  __syncthreads();  // tile 1 resident; all waves done reading K(0)

  int vcur = 0;  // V buffer slot of tile kt (mod 3)
  for (int kt = 0; kt < 32; kt++) {
    const int knew = kt & 1;            // K slot holding dead K(kt) -> refill
    const int kread = knew ^ 1;         // K slot holding K(kt+1)
    int vn2 = vcur + 2; if (vn2 >= 3) vn2 -= 3;  // V slot for tile kt+2

    if (kt <= 29) {  // async prefetch tile kt+2
#pragma unroll
      for (int r = 0; r < 3; r++)
        GLL(gbase + goffs[r],
            (isK ? (stK0 + knew * 6144) : (stV0 + vn2 * 6144)) + ldoffs[r]);
#pragma unroll
      for (int r = 0; r < 3; r++) goffs[r] += inc;
    }

    // ---- stream 1: S(kt+1) from K(kt+1) ----
    f32x4 sacc[2][4];
    if (kt <= 30) {
      const __bf16* Kc = Ks + (kread * 2 + grp) * 3072;
#pragma unroll
      for (int kk = 0; kk < 2; kk++) {
        bf16x8 kf[3];
#pragma unroll
        for (int ks = 0; ks < 3; ks++)
          kf[ks] = *(const bf16x8*)&Kc[(kk * 16 + l15) * 96 + ks * 32 + l4 * 8];
#pragma unroll
        for (int mt = 0; mt < 4; mt++) sacc[kk][mt] = (f32x4){0.f, 0.f, 0.f, 0.f};
#pragma unroll
        for (int ks = 0; ks < 3; ks++)
#pragma unroll
          for (int mt = 0; mt < 4; mt++)
            sacc[kk][mt] =
                __builtin_amdgcn_mfma_f32_16x16x32_bf16(kf[ks], qf[mt][ks], sacc[kk][mt], 0, 0, 0);
      }
    }

    // ---- stream 2: PV(kt): O += P(64x32) . V(32x96) ----
    {
      const __bf16* Vc = Vs + (vcur * 2 + grp) * 3072;
      bf16x8 pf[4];
#pragma unroll
      for (int mt = 0; mt < 4; mt++)
        pf[mt] = *(const bf16x8*)&Pw[(mt * 16 + l15) * PSTR + l4 * 8];
#pragma unroll
      for (int nt = 0; nt < 6; nt++) {
        bf16x8 vf = *(const bf16x8*)&Vc[(nt * 16 + l15) * 32 + l4 * 8];
#pragma unroll
        for (int mt = 0; mt < 4; mt++)
          oacc[mt][nt] = __builtin_amdgcn_mfma_f32_16x16x32_bf16(pf[mt], vf, oacc[mt][nt], 0, 0, 0);
      }
    }

    // ---- exp(kt+1) -> P write (after this wave's Ps reads; wave-private) ----
    if (kt <= 30) {
#pragma unroll
      for (int kk = 0; kk < 2; kk++)
#pragma unroll
        for (int mt = 0; mt < 4; mt++) {
          float p0 = __builtin_amdgcn_exp2f(sacc[kk][mt][0]);
          float p1 = __builtin_amdgcn_exp2f(sacc[kk][mt][1]);
          float p2 = __builtin_amdgcn_exp2f(sacc[kk][mt][2]);
          float p3 = __builtin_amdgcn_exp2f(sacc[kk][mt][3]);
          lacc[mt] += (p0 + p1) + (p2 + p3);
          bf16x4 pb;
          pb[0] = (__bf16)p0; pb[1] = (__bf16)p1; pb[2] = (__bf16)p2; pb[3] = (__bf16)p3;
          *(bf16x4*)&Pw[(mt * 16 + l15) * PSTR + kk * 16 + l4 * 4] = pb;
        }
    }

    vcur += 1; if (vcur >= 3) vcur -= 3;
    __syncthreads();  // drains GLL(kt+2); all waves done reading K(kt+1)/V(kt)
  }

  // per-group denominators -> Ls[grp][256]
#pragma unroll
  for (int mt = 0; mt < 4; mt++) {
    float s = lacc[mt];
    s += __shfl_xor(s, 16);
    s += __shfl_xor(s, 32);
    if (l4 == 0) Ls[grp * 256 + wgrp * 64 + mt * 16 + l15] = s;
  }
  // group 1 parks partial O (fp32) in FB (reuses K/V/P space; post-loop barrier passed)
  if (grp == 1) {
#pragma unroll
    for (int mt = 0; mt < 4; mt++)
#pragma unroll
      for (int nt = 0; nt < 6; nt++)
#pragma unroll
        for (int r = 0; r < 4; r++)
          FB[wgrp * 6144 + (mt * 16 + l4 * 4 + r) * 96 + nt * 16 + l15] = oacc[mt][nt][r];
  }
  __syncthreads();
  // group 0 merges + normalizes + stores
  if (grp == 0) {
#pragma unroll
    for (int mt = 0; mt < 4; mt++)
#pragma unroll
      for (int r = 0; r < 4; r++) {
        int rowl = wgrp * 64 + mt * 16 + l4 * 4 + r;
        float inv = 1.0f / (Ls[rowl] + Ls[256 + rowl]);
        int row = qt * 256 + rowl;
        __bf16* po = o + (size_t)(b * SC + row) * DIMC + h * HDC;
#pragma unroll
        for (int nt = 0; nt < 6; nt++) {
          float v = oacc[mt][nt][r] +
                    FB[wgrp * 6144 + (mt * 16 + l4 * 4 + r) * 96 + nt * 16 + l15];
          po[nt * 16 + l15] = (__bf16)(v * inv);
        }
      }
  }
}

// ---------------------------------------------------------------------------
extern "C" void kernel_launch(void* const* d_in, const int* in_sizes, int n_in,
                              void* d_out, int out_size, void* d_ws, size_t ws_size,
                              hipStream_t stream) {
  const int* xyz = (const int*)d_in[0];
  const float* h = (const float*)d_in[1];
  const float* wq = (const float*)d_in[2];
  const float* wk = (const float*)d_in[3];
  const float* wv = (const float*)d_in[4];
  const float* wo = (const float*)d_in[5];
  float* out = (float*)d_out;

  __bf16* p = (__bf16*)d_ws;
  __bf16* hb = p;  p += (size_t)BSC * DIMC;
  __bf16* wqb = p; p += (size_t)DIMC * DIMC;
  __bf16* wkb = p; p += (size_t)DIMC * DIMC;
  __bf16* wvb = p; p += (size_t)DIMC * DIMC;
  __bf16* wob = p; p += (size_t)DIMC * DIMC;
  __bf16* qb = p;  p += (size_t)BSC * DIMC;
  __bf16* kb = p;  p += (size_t)BSC * DIMC;
  __bf16* vTb = p; p += (size_t)BSC * DIMC;
  __bf16* ab = p;  p += (size_t)BSC * DIMC;
  float2* rt = (float2*)p;  // 4096*48 float2 = 1.5 MB

  cvt_bf16_k<<<dim3(1920), 256, 0, stream>>>(h, wq, wk, wv, wo, hb, wqb, wkb, wvb, wob,
                                             xyz, rt);
  gemm_qkv_k<<<dim3(32, 12, 3), 256, 0, stream>>>(hb, wqb, wkb, wvb, rt, qb, kb, vTb);
  attn_k<<<dim3(SC / 256, BC * NHC), 512, 0, stream>>>(qb, kb, vTb, ab);
  gemm_out_k<<<dim3(32, 12), 256, 0, stream>>>(ab, wob, out);
}

// Round 9
// 258.811 us; speedup vs baseline: 1.0530x; 1.0530x over previous
//
#include <hip/hip_runtime.h>
#include <hip/hip_bf16.h>

#define DIMC 1536
#define NHC 16
#define HDC 96
#define BC 2
#define SC 2048
#define BSC (BC*SC)   // 4096 rows total

typedef __bf16 bf16x8 __attribute__((ext_vector_type(8)));
typedef __bf16 bf16x4 __attribute__((ext_vector_type(4)));
typedef float f32x4 __attribute__((ext_vector_type(4)));

// async global->LDS, 16B per lane: lane i -> lds_base + i*16 (lds base wave-uniform)
#define GLL(g, l)                                                              \
  __builtin_amdgcn_global_load_lds(                                            \
      (const __attribute__((address_space(1))) unsigned int*)(const void*)(g), \
      (__attribute__((address_space(3))) unsigned int*)(void*)(l), 16, 0, 0)

// (1/sqrt(96)) * log2(e): Q is pre-scaled by this so attention uses exp2 directly
#define QSCALE 0.14724448646421423f

// ---------------------------------------------------------------------------
// fp32 -> bf16 conversion (y=0..4) + RoPE table build (y=5).
// rt[(row*3+axis)*16 + f] = (cos, sin) of xyz[row*3+axis]*10000^(-f/16)
// ---------------------------------------------------------------------------
__global__ __launch_bounds__(256) void cvt_bf16_k(
    const float* __restrict__ s0, const float* __restrict__ s1,
    const float* __restrict__ s2, const float* __restrict__ s3,
    const float* __restrict__ s4,
    __bf16* __restrict__ d0, __bf16* __restrict__ d1, __bf16* __restrict__ d2,
    __bf16* __restrict__ d3, __bf16* __restrict__ d4,
    const int* __restrict__ xyz, float2* __restrict__ rt) {
  int r = blockIdx.y;
  if (r == 5) {
    int idx = blockIdx.x * 256 + threadIdx.x;
    if (idx < BSC * 48) {
      int f = idx & 15;
      int ra = idx >> 4;  // row*3 + axis
      float invf = exp2f(-0.8304820237f * (float)f);
      float ang = (float)xyz[ra] * invf;
      float sn, cs;
      __sincosf(ang, &sn, &cs);
      rt[idx] = make_float2(cs, sn);
    }
    return;
  }
  const float* srcs[5] = {s0, s1, s2, s3, s4};
  __bf16* dsts[5] = {d0, d1, d2, d3, d4};
  const int ns[5] = {BSC * DIMC, DIMC * DIMC, DIMC * DIMC, DIMC * DIMC, DIMC * DIMC};
  const float* src = srcs[r];
  __bf16* dst = dsts[r];
  int n = ns[r];
  int idx = (blockIdx.x * 256 + threadIdx.x) * 8;
  int stride = gridDim.x * 256 * 8;
  for (; idx < n; idx += stride) {
    float4 a = *(const float4*)(src + idx);
    float4 b = *(const float4*)(src + idx + 4);
    __bf16 o[8];
    o[0] = (__bf16)a.x; o[1] = (__bf16)a.y; o[2] = (__bf16)a.z; o[3] = (__bf16)a.w;
    o[4] = (__bf16)b.x; o[5] = (__bf16)b.y; o[6] = (__bf16)b.z; o[7] = (__bf16)b.w;
    *(uint4*)(dst + idx) = *(const uint4*)o;
  }
}

// ---------------------------------------------------------------------------
// GEMM core: C[4096,1536] = A * Bm^T, 128x128 tile, BK=64, GLL staging,
// XOR-swizzled LDS (row stride 64 elems = 128B; chunk' = chunk ^ (row&7)).
// ---------------------------------------------------------------------------
__device__ __forceinline__ void gemm_core(const __bf16* __restrict__ A,
                                          const __bf16* __restrict__ Bm,
                                          int bm, int bn, f32x4 acc[4][4],
                                          __bf16* As, __bf16* Bs) {
  const int t = threadIdx.x;
  const int wave = t >> 6, lane = t & 63;
  const int l15 = lane & 15, l4 = lane >> 4;
  const int wm = (wave >> 1) * 64, wn = (wave & 1) * 64;

  const int srow8 = lane >> 3;                 // 0..7
  const int scol = ((lane & 7) ^ srow8) * 8;   // swizzled global col chunk
  const __bf16* gA = A + (size_t)(bm * 128 + wave * 32 + srow8) * DIMC + scol;
  const __bf16* gB = Bm + (size_t)(bn * 128 + wave * 32 + srow8) * DIMC + scol;
  __bf16* lA = As + wave * 2048;
  __bf16* lB = Bs + wave * 2048;

  for (int k0 = 0; k0 < DIMC; k0 += 64) {
    __syncthreads();
#pragma unroll
    for (int c = 0; c < 4; c++) {
      GLL(gA + c * 8 * DIMC, lA + c * 512);
      GLL(gB + c * 8 * DIMC, lB + c * 512);
    }
    gA += 64; gB += 64;
    __syncthreads();
#pragma unroll
    for (int k2 = 0; k2 < 2; k2++) {
      bf16x8 af[4], bfr[4];
#pragma unroll
      for (int i = 0; i < 4; i++) {
        int row = wm + i * 16 + l15;
        af[i] = *(const bf16x8*)&As[row * 64 + (((k2 * 4 + l4) ^ (l15 & 7)) * 8)];
      }
#pragma unroll
      for (int j = 0; j < 4; j++) {
        int row = wn + j * 16 + l15;
        bfr[j] = *(const bf16x8*)&Bs[row * 64 + (((k2 * 4 + l4) ^ (l15 & 7)) * 8)];
      }
#pragma unroll
      for (int i = 0; i < 4; i++)
#pragma unroll
        for (int j = 0; j < 4; j++)
          acc[i][j] = __builtin_amdgcn_mfma_f32_16x16x32_bf16(af[i], bfr[j], acc[i][j], 0, 0, 0);
    }
  }
}

// QKV GEMM: z=0 -> q (rope, pre-scaled), z=1 -> k (rope), z=2 -> v transposed to vT[bh][d][s]
__global__ __launch_bounds__(256, 2) void gemm_qkv_k(
    const __bf16* __restrict__ A, const __bf16* __restrict__ W0,
    const __bf16* __restrict__ W1, const __bf16* __restrict__ W2,
    const float2* __restrict__ rt,
    __bf16* __restrict__ qo, __bf16* __restrict__ ko, __bf16* __restrict__ vT) {
  __shared__ __bf16 As[128 * 64];
  __shared__ __bf16 Bs[128 * 64];
  const int z = blockIdx.z;
  const __bf16* W = (z == 0) ? W0 : (z == 1) ? W1 : W2;
  f32x4 acc[4][4] = {};
  gemm_core(A, W, blockIdx.x, blockIdx.y, acc, As, Bs);

  const int t = threadIdx.x;
  const int wave = t >> 6, lane = t & 63;
  const int l15 = lane & 15, l4 = lane >> 4;
  const int wm = (wave >> 1) * 64, wn = (wave & 1) * 64;

  if (z < 2) {
    __bf16* C = (z == 0) ? qo : ko;
    const float qs = (z == 0) ? QSCALE : 1.0f;
#pragma unroll
    for (int jp = 0; jp < 2; jp++) {
      int colbase = blockIdx.y * 128 + wn + jp * 32;
      int axis = (colbase % 96) >> 5;  // wave-uniform
#pragma unroll
      for (int i = 0; i < 4; i++) {
#pragma unroll
        for (int r = 0; r < 4; r++) {
          int row = blockIdx.x * 128 + wm + i * 16 + l4 * 4 + r;
          float2 t2 = rt[(row * 3 + axis) * 16 + l15];
          float e = acc[i][2 * jp][r], od = acc[i][2 * jp + 1][r];
          C[(size_t)row * DIMC + colbase + l15] = (__bf16)((e * t2.x - od * t2.y) * qs);
          C[(size_t)row * DIMC + colbase + l15 + 16] = (__bf16)((od * t2.x + e * t2.y) * qs);
        }
      }
    }
  } else {
#pragma unroll
    for (int i = 0; i < 4; i++)
#pragma unroll
      for (int j = 0; j < 4; j++) {
        int row0 = blockIdx.x * 128 + wm + i * 16 + l4 * 4;
        int col = blockIdx.y * 128 + wn + j * 16 + l15;
        int head = col / 96, d = col % 96;
        int b = row0 >> 11, s = row0 & 2047;
        bf16x4 pk;
#pragma unroll
        for (int r = 0; r < 4; r++) pk[r] = (__bf16)acc[i][j][r];
        *(bf16x4*)(vT + ((size_t)(b * 16 + head) * 96 + d) * 2048 + s) = pk;
      }
  }
}

__global__ __launch_bounds__(256, 2) void gemm_out_k(const __bf16* __restrict__ A,
                                                     const __bf16* __restrict__ W,
                                                     float* __restrict__ C) {
  __shared__ __bf16 As[128 * 64];
  __shared__ __bf16 Bs[128 * 64];
  f32x4 acc[4][4] = {};
  gemm_core(A, W, blockIdx.x, blockIdx.y, acc, As, Bs);
  const int t = threadIdx.x;
  const int wave = t >> 6, lane = t & 63;
  const int l15 = lane & 15, l4 = lane >> 4;
  const int wm = (wave >> 1) * 64, wn = (wave & 1) * 64;
#pragma unroll
  for (int i = 0; i < 4; i++)
#pragma unroll
    for (int j = 0; j < 4; j++) {
      int row = blockIdx.x * 128 + wm + i * 16 + l4 * 4;
      int col = blockIdx.y * 128 + wn + j * 16 + l15;
#pragma unroll
      for (int r = 0; r < 4; r++)
        C[(size_t)(row + r) * DIMC + col] = acc[i][j][r];
    }
}

// ---------------------------------------------------------------------------
// Flash attention, linear softmax (exp2, Q pre-scaled). In-block key split:
// 512 threads = 8 waves = 2 key-groups x 4 waves. Group g covers keys
// [g*1024,(g+1)*1024) in 32-key tiles (32 iters), over the SAME 256 q rows
// (wave owns 64 q rows). GLL double-buffered K/V, 1 barrier/iter. Partial
// O (fp32) + denominators merged through LDS at the end (linear => pure add).
// Within each group: waves 0-1 stage K, waves 2-3 stage V.  [r4-proven]
// ---------------------------------------------------------------------------
__global__ __launch_bounds__(512, 2) void attn_k(const __bf16* __restrict__ q,
                                                 const __bf16* __restrict__ k,
                                                 const __bf16* __restrict__ vT,
                                                 __bf16* __restrict__ o) {
  const int qt = blockIdx.x;    // 0..7 (256 q rows each)
  const int bh = blockIdx.y;
  const int b = bh >> 4, h = bh & 15;
  const int t = threadIdx.x;
  const int wave = t >> 6, lane = t & 63;
  const int l15 = lane & 15, l4 = lane >> 4;
  const int grp = wave >> 2, wgrp = wave & 3;

  // smem: Ks[2][2][32*96] | Vs[2][2][96*32] | Ps[8][64*72] | Ls[2][256]
  // final phase reuses Ks/Vs/Ps region as FB = float[4][64*96]
  __shared__ __attribute__((aligned(16))) char smem[124928];
  __bf16* Ks = (__bf16*)smem;
  __bf16* Vs = (__bf16*)(smem + 24576);
  __bf16* Ps = (__bf16*)(smem + 49152);
  float* Ls = (float*)(smem + 122880);
  float* FB = (float*)smem;

  // Q fragments (persist all iters); q rows = qt*256 + wgrp*64 + mt*16 + l15
  bf16x8 qf[4][3];
  {
    const __bf16* gq =
        q + (size_t)(b * SC + qt * 256 + wgrp * 64 + l15) * DIMC + h * HDC + l4 * 8;
#pragma unroll
    for (int mt = 0; mt < 4; mt++)
#pragma unroll
      for (int ks = 0; ks < 3; ks++)
        qf[mt][ks] = *(const bf16x8*)(gq + (size_t)mt * 16 * DIMC + ks * 32);
  }

  // staging role: waves 0-1 of group stage K tile (32x96), waves 2-3 stage V tile (96x32)
  const bool isK = (wgrp < 2);
  const int cw = isK ? wgrp : (wgrp - 2);  // 0/1
  const __bf16* gbase = isK ? k : vT;
  const int inc = isK ? 32 * DIMC : 32;
  int goffs[3];
  int ldoffs[3];
#pragma unroll
  for (int r = 0; r < 3; r++) {
    int off = (cw * 3 + r) * 512 + lane * 8;  // elem offset within 6KB half-tile
    ldoffs[r] = (cw * 3 + r) * 512;
    if (isK) {
      int key = off / 96, d = off % 96;
      goffs[r] = (b * SC + grp * 1024 + key) * DIMC + h * HDC + d;
    } else {
      int d = off >> 5, key = off & 31;
      goffs[r] = (bh * HDC + d) * SC + grp * 1024 + key;
    }
  }

  // prologue: stage tile 0 into buffer 0
#pragma unroll
  for (int r = 0; r < 3; r++) {
    __bf16* dst = (isK ? (Ks + grp * 3072) : (Vs + grp * 3072)) + ldoffs[r];
    GLL(gbase + goffs[r], dst);
  }
  __syncthreads();

  f32x4 oacc[4][6] = {};
  float lacc[4] = {0.f, 0.f, 0.f, 0.f};
  __bf16* Pw = &Ps[wave * 4608];

  for (int kt = 0; kt < 32; kt++) {
    const int cur = kt & 1, nxt = cur ^ 1;
    if (kt + 1 < 32) {  // async prefetch next 32-key tile
#pragma unroll
      for (int r = 0; r < 3; r++) {
        goffs[r] += inc;
        __bf16* dst =
            (isK ? (Ks + (nxt * 2 + grp) * 3072) : (Vs + (nxt * 2 + grp) * 3072)) + ldoffs[r];
        GLL(gbase + goffs[r], dst);
      }
    }
    const __bf16* Kc = Ks + (cur * 2 + grp) * 3072;  // [32][96]
    const __bf16* Vc = Vs + (cur * 2 + grp) * 3072;  // [96][32]

    // S^T = K.Q^T per 16-key subtile; exp2 + packed P write
#pragma unroll
    for (int kk = 0; kk < 2; kk++) {
      bf16x8 kf[3];
#pragma unroll
      for (int ks = 0; ks < 3; ks++)
        kf[ks] = *(const bf16x8*)&Kc[(kk * 16 + l15) * 96 + ks * 32 + l4 * 8];
      f32x4 sacc[4] = {};
#pragma unroll
      for (int ks = 0; ks < 3; ks++)
#pragma unroll
        for (int mt = 0; mt < 4; mt++)
          sacc[mt] = __builtin_amdgcn_mfma_f32_16x16x32_bf16(kf[ks], qf[mt][ks], sacc[mt], 0, 0, 0);
#pragma unroll
      for (int mt = 0; mt < 4; mt++) {
        float p0 = __builtin_amdgcn_exp2f(sacc[mt][0]);
        float p1 = __builtin_amdgcn_exp2f(sacc[mt][1]);
        float p2 = __builtin_amdgcn_exp2f(sacc[mt][2]);
        float p3 = __builtin_amdgcn_exp2f(sacc[mt][3]);
        lacc[mt] += (p0 + p1) + (p2 + p3);
        bf16x4 pb;
        pb[0] = (__bf16)p0; pb[1] = (__bf16)p1; pb[2] = (__bf16)p2; pb[3] = (__bf16)p3;
        *(bf16x4*)&Pw[(mt * 16 + l15) * 72 + kk * 16 + l4 * 4] = pb;
      }
    }

    // O += P(64x32) . V(32x96)
    {
      bf16x8 pf[4];
#pragma unroll
      for (int mt = 0; mt < 4; mt++)
        pf[mt] = *(const bf16x8*)&Pw[(mt * 16 + l15) * 72 + l4 * 8];
#pragma unroll
      for (int nt = 0; nt < 6; nt++) {
        bf16x8 vf = *(const bf16x8*)&Vc[(nt * 16 + l15) * 32 + l4 * 8];
#pragma unroll
        for (int mt = 0; mt < 4; mt++)
          oacc[mt][nt] = __builtin_amdgcn_mfma_f32_16x16x32_bf16(pf[mt], vf, oacc[mt][nt], 0, 0, 0);
      }
    }
    __syncthreads();  // drains prefetch GLLs; all waves done reading cur
  }

  // per-group denominators -> Ls[grp][256]
#pragma unroll
  for (int mt = 0; mt < 4; mt++) {
    float s = lacc[mt];
    s += __shfl_xor(s, 16);
    s += __shfl_xor(s, 32);
    if (l4 == 0) Ls[grp * 256 + wgrp * 64 + mt * 16 + l15] = s;
  }
  // group 1 parks partial O in LDS (fp32)
  if (grp == 1) {
#pragma unroll
    for (int mt = 0; mt < 4; mt++)
#pragma unroll
      for (int nt = 0; nt < 6; nt++)
#pragma unroll
        for (int r = 0; r < 4; r++)
          FB[wgrp * 6144 + (mt * 16 + l4 * 4 + r) * 96 + nt * 16 + l15] = oacc[mt][nt][r];
  }
  __syncthreads();
  // group 0 merges + normalizes + stores
  if (grp == 0) {
#pragma unroll
    for (int mt = 0; mt < 4; mt++)
#pragma unroll
      for (int r = 0; r < 4; r++) {
        int rowl = wgrp * 64 + mt * 16 + l4 * 4 + r;
        float inv = 1.0f / (Ls[rowl] + Ls[256 + rowl]);
        int row = qt * 256 + rowl;
        __bf16* po = o + (size_t)(b * SC + row) * DIMC + h * HDC;
#pragma unroll
        for (int nt = 0; nt < 6; nt++) {
          float v = oacc[mt][nt][r] +
                    FB[wgrp * 6144 + (mt * 16 + l4 * 4 + r) * 96 + nt * 16 + l15];
          po[nt * 16 + l15] = (__bf16)(v * inv);
        }
      }
  }
}

// ---------------------------------------------------------------------------
extern "C" void kernel_launch(void* const* d_in, const int* in_sizes, int n_in,
                              void* d_out, int out_size, void* d_ws, size_t ws_size,
                              hipStream_t stream) {
  const int* xyz = (const int*)d_in[0];
  const float* h = (const float*)d_in[1];
  const float* wq = (const float*)d_in[2];
  const float* wk = (const float*)d_in[3];
  const float* wv = (const float*)d_in[4];
  const float* wo = (const float*)d_in[5];
  float* out = (float*)d_out;

  __bf16* p = (__bf16*)d_ws;
  __bf16* hb = p;  p += (size_t)BSC * DIMC;
  __bf16* wqb = p; p += (size_t)DIMC * DIMC;
  __bf16* wkb = p; p += (size_t)DIMC * DIMC;
  __bf16* wvb = p; p += (size_t)DIMC * DIMC;
  __bf16* wob = p; p += (size_t)DIMC * DIMC;
  __bf16* qb = p;  p += (size_t)BSC * DIMC;
  __bf16* kb = p;  p += (size_t)BSC * DIMC;
  __bf16* vTb = p; p += (size_t)BSC * DIMC;
  __bf16* ab = p;  p += (size_t)BSC * DIMC;
  float2* rt = (float2*)p;  // 4096*48 float2 = 1.5 MB

  cvt_bf16_k<<<dim3(3072, 6), 256, 0, stream>>>(h, wq, wk, wv, wo, hb, wqb, wkb, wvb, wob,
                                                xyz, rt);
  gemm_qkv_k<<<dim3(32, 12, 3), 256, 0, stream>>>(hb, wqb, wkb, wvb, rt, qb, kb, vTb);
  attn_k<<<dim3(SC / 256, BC * NHC), 512, 0, stream>>>(qb, kb, vTb, ab);
  gemm_out_k<<<dim3(32, 12), 256, 0, stream>>>(ab, wob, out);
}